// Round 1
// 436.180 us; speedup vs baseline: 1.4326x; 1.4326x over previous
//
#include <hip/hip_runtime.h>
#include <cstdint>
#include <cstddef>

typedef short s16x8 __attribute__((ext_vector_type(8)));
typedef short s16x4 __attribute__((ext_vector_type(4)));
typedef float f32x4 __attribute__((ext_vector_type(4)));

#define NB 1576
#define NT 30
#define ND 1024
#define NH 128
#define LNEPS 1e-5f
#define ATT_SCALE 0.08838834764831845f  // sqrt(1/128)

// ---------------- workspace layout (bytes) ----------------
#define WS_W1P   0          // 1024x128 bf16 packed = 262144
#define WS_W2P   262144     // 128x1024 bf16 packed = 262144
#define WS_WQP   524288     // 128x128 = 32768
#define WS_WKP   557056
#define WS_WVP   589824
#define WS_WOP   622592
#define WS_PAR   655360     // 3108 fp32 = 12432
#define WS_NEED  667792

// par[] layout (float indices)
#define P_B1   0
#define P_LNG  128
#define P_LNB  256
#define P_TB   384        // 32 slots, 30 used
#define P_TW   416        // 900
#define P_BQ   1316
#define P_BK   1444
#define P_BV   1572
#define P_BO   1700
#define P_NG   1828
#define P_NB_  1956
#define P_B2   2084       // 1024
#define P_CNT  3108

static __device__ __forceinline__ float bf2f(short s) {
  union { unsigned int u; float f; } c;
  c.u = ((unsigned int)(unsigned short)s) << 16;
  return c.f;
}
static __device__ __forceinline__ short f2bf(float f) {
  union { __bf16 h; short s; } c;
  c.h = (__bf16)f;            // RNE convert
  return c.s;
}
static __device__ __forceinline__ float ldp(const void* p, int i, int isf32) {
  return isf32 ? ((const float*)p)[i] : bf2f(((const short*)p)[i]);
}
// fallback-path fragment load (8 strided scalars) — kept for ws-too-small path
static __device__ __forceinline__ s16x8 ldfragB(const void* W, int N, int k0, int n0,
                                                int m_, int quad, int isf32) {
  s16x8 r;
  int k = k0 + quad*8, n = n0 + m_;
  if (isf32) {
    const float* p = (const float*)W + (size_t)k*N + n;
#pragma unroll
    for (int j = 0; j < 8; j++) r[j] = f2bf(p[(size_t)j*N]);
  } else {
    const short* p = (const short*)W + (size_t)k*N + n;
#pragma unroll
    for (int j = 0; j < 8; j++) r[j] = p[(size_t)j*N];
  }
  return r;
}
static __device__ __forceinline__ void mm32d(const short* Ab, const void* W, const void* bias,
                                             int w, int lane, int isf32,
                                             f32x4 acc[2][2], float bias2[2]) {
  int m_ = lane & 15, quad = lane >> 4;
#pragma unroll
  for (int mt = 0; mt < 2; mt++)
#pragma unroll
    for (int j = 0; j < 2; j++) acc[mt][j] = {0.f, 0.f, 0.f, 0.f};
  bias2[0] = ldp(bias, (2*w)*16 + m_, isf32);
  bias2[1] = ldp(bias, (2*w+1)*16 + m_, isf32);
#pragma unroll
  for (int ks = 0; ks < 4; ks++) {
    s16x8 a[2];
#pragma unroll
    for (int mt = 0; mt < 2; mt++)
      a[mt] = *(const s16x8*)(Ab + (mt*16 + m_)*136 + (ks*4 + quad)*8);
#pragma unroll
    for (int j = 0; j < 2; j++) {
      s16x8 bb = ldfragB(W, NH, ks*32, (2*w + j)*16, m_, quad, isf32);
#pragma unroll
      for (int mt = 0; mt < 2; mt++)
        acc[mt][j] = __builtin_amdgcn_mfma_f32_16x16x32_bf16(a[mt], bb, acc[mt][j], 0, 0, 0);
    }
  }
}

// ================= prep kernel: repack weights -> bf16 fragment layout =================
// packed layout for W[K][N]: frag t = kq*N + n holds W[kq*8 + j][n], j=0..7, as s16x8.
// MFMA B-fragment (k0,n0) for lane (m_,quad) = one 16B load at ((k0/8+quad)*N + n0+m_)*8.
__global__ __launch_bounds__(256) void repack(
    const void* __restrict__ x,
    const void* __restrict__ W1, const void* __restrict__ Wq, const void* __restrict__ Wk,
    const void* __restrict__ Wv, const void* __restrict__ Wo, const void* __restrict__ W2,
    const void* __restrict__ b1, const void* __restrict__ ln_g, const void* __restrict__ ln_b,
    const void* __restrict__ T_W, const void* __restrict__ T_b,
    const void* __restrict__ bq, const void* __restrict__ bk, const void* __restrict__ bv,
    const void* __restrict__ bo, const void* __restrict__ n_g, const void* __restrict__ n_b,
    const void* __restrict__ b2,
    short* __restrict__ W1p, short* __restrict__ W2p,
    short* __restrict__ Wqp, short* __restrict__ Wkp, short* __restrict__ Wvp,
    short* __restrict__ Wop, float* __restrict__ par) {
  // dtype sniff on x (same criterion as main kernel), wave-parallel
  int lane = threadIdx.x & 63;
  const unsigned short* u = (const unsigned short*)x;
  int e = (u[lane] >> 7) & 0xFF;
  unsigned long long bal = __ballot(e >= 0x3A && e <= 0x43);
  int isf32 = (__popcll(bal) < 48) ? 1 : 0;

  int idx = blockIdx.x * 256 + threadIdx.x;
  if (idx < 16384) {                   // W1: K8=128, N=128
    int t = idx, kq = t >> 7, n = t & 127;
    s16x8 v;
#pragma unroll
    for (int j = 0; j < 8; j++)
      v[j] = isf32 ? f2bf(((const float*)W1)[(size_t)(kq*8 + j)*128 + n])
                   : ((const short*)W1)[(size_t)(kq*8 + j)*128 + n];
    *(s16x8*)(W1p + (size_t)t*8) = v;
  } else if (idx < 32768) {            // W2: K8=16, N=1024
    int t = idx - 16384, kq = t >> 10, n = t & 1023;
    s16x8 v;
#pragma unroll
    for (int j = 0; j < 8; j++)
      v[j] = isf32 ? f2bf(((const float*)W2)[(size_t)(kq*8 + j)*1024 + n])
                   : ((const short*)W2)[(size_t)(kq*8 + j)*1024 + n];
    *(s16x8*)(W2p + (size_t)t*8) = v;
  } else if (idx < 40960) {            // Wq/Wk/Wv/Wo: 2048 frags each, K8=16, N=128
    int t = idx - 32768;
    int sel = t >> 11;
    int tt = t & 2047, kq = tt >> 7, n = tt & 127;
    const void* W = (sel == 0) ? Wq : (sel == 1) ? Wk : (sel == 2) ? Wv : Wo;
    short* Wp = (sel == 0) ? Wqp : (sel == 1) ? Wkp : (sel == 2) ? Wvp : Wop;
    s16x8 v;
#pragma unroll
    for (int j = 0; j < 8; j++)
      v[j] = isf32 ? f2bf(((const float*)W)[(size_t)(kq*8 + j)*128 + n])
                   : ((const short*)W)[(size_t)(kq*8 + j)*128 + n];
    *(s16x8*)(Wp + (size_t)tt*8) = v;
  } else {
    int t = idx - 40960;
    if (t < P_CNT) {
      float v;
      if (t < 128)        v = ldp(b1,   t,        isf32);
      else if (t < 256)   v = ldp(ln_g, t - 128,  isf32);
      else if (t < 384)   v = ldp(ln_b, t - 256,  isf32);
      else if (t < 416) { int i = t - 384; v = (i < NT) ? ldp(T_b, i, isf32) : 0.f; }
      else if (t < 1316)  v = ldp(T_W, t - 416,   isf32);
      else if (t < 1444)  v = ldp(bq,  t - 1316,  isf32);
      else if (t < 1572)  v = ldp(bk,  t - 1444,  isf32);
      else if (t < 1700)  v = ldp(bv,  t - 1572,  isf32);
      else if (t < 1828)  v = ldp(bo,  t - 1700,  isf32);
      else if (t < 1956)  v = ldp(n_g, t - 1828,  isf32);
      else if (t < 2084)  v = ldp(n_b, t - 1956,  isf32);
      else                v = ldp(b2,  t - 2084,  isf32);
      par[t] = v;
    }
  }
}

// ================= fast fused kernel: 512 threads (8 waves), packed weights =================
// wave w owns output col-group g = w (cols w*16 .. w*16+15 of H=128)
__global__ __launch_bounds__(512, 4) void fused_pk(
    const void* __restrict__ x,
    const short* __restrict__ W1p, const short* __restrict__ W2p,
    const short* __restrict__ Wqp, const short* __restrict__ Wkp,
    const short* __restrict__ Wvp, const short* __restrict__ Wop,
    const float* __restrict__ par, void* __restrict__ out) {
  __shared__ __align__(16) short As[32*136];     // x K-slab staging; later av
  __shared__ __align__(16) float hbuf[NT*128];   // h fp32 -> h2 (residual)
  __shared__ float g0s[32];
  __shared__ float sgate[32];
  __shared__ __align__(16) short hn[32*136];     // LN2 out; later h3
  __shared__ __align__(16) short qb[32*136];     // q; later out staging (bf16 path)
  __shared__ __align__(16) short kbf[32*136];    // k
  __shared__ __align__(16) short vt[NH*32];      // v^T [channel][time]
  __shared__ float Sb[32*33];
  __shared__ __align__(16) short Pb[32*32];
  // total LDS = 64,896 B (< 64 KiB) -> 2 blocks/CU x 8 waves = 16 waves/CU

  int tid = threadIdx.x, lane = tid & 63, w = tid >> 6;
  int m_ = lane & 15, quad = lane >> 4;
  int b = blockIdx.x;
  const int g16 = w*16 + m_;          // this lane's output column in [0,128)

  // dtype sniff (wave-parallel ballot, same criterion as before)
  int isf32;
  {
    const unsigned short* u = (const unsigned short*)x;
    int e = (u[lane] >> 7) & 0xFF;
    unsigned long long bal = __ballot(e >= 0x3A && e <= 0x43);
    isf32 = (__popcll(bal) < 48) ? 1 : 0;
  }
  const size_t xbase = (size_t)b * NT * ND;

  // ---- phase 1: C = x @ W1 (32x128, K=1024), reg-double-buffered x staging ----
  f32x4 acc0 = {0.f,0.f,0.f,0.f}, acc1 = {0.f,0.f,0.f,0.f};
  {
    int r_st = tid >> 4, cc_st = tid & 15;       // 512 threads = 32 rows x 16 chunks
    int rr = r_st > NT-1 ? NT-1 : r_st;
    const size_t xoff0 = xbase + (size_t)rr*ND + cc_st*8;
    float4 pf0, pf1; uint4 pu;
    if (isf32) { const float* s = (const float*)x + xoff0; pf0 = *(const float4*)s; pf1 = *(const float4*)(s + 4); }
    else       { pu = *(const uint4*)((const short*)x + xoff0); }
    for (int kb = 0; kb < 8; kb++) {
      if (isf32) {
        s16x8 t;
        t[0]=f2bf(pf0.x); t[1]=f2bf(pf0.y); t[2]=f2bf(pf0.z); t[3]=f2bf(pf0.w);
        t[4]=f2bf(pf1.x); t[5]=f2bf(pf1.y); t[6]=f2bf(pf1.z); t[7]=f2bf(pf1.w);
        *(s16x8*)(As + r_st*136 + cc_st*8) = t;
      } else {
        *(uint4*)(As + r_st*136 + cc_st*8) = pu;
      }
      __syncthreads();
      if (kb < 7) {                              // prefetch next slab under compute
        size_t o = xoff0 + (size_t)(kb + 1)*128;
        if (isf32) { const float* s = (const float*)x + o; pf0 = *(const float4*)s; pf1 = *(const float4*)(s + 4); }
        else       { pu = *(const uint4*)((const short*)x + o); }
      }
#pragma unroll
      for (int kblk = 0; kblk < 4; kblk++) {
        s16x8 a0 = *(const s16x8*)(As + m_*136 + (kblk*4 + quad)*8);
        s16x8 a1 = *(const s16x8*)(As + (16 + m_)*136 + (kblk*4 + quad)*8);
        s16x8 bb = *(const s16x8*)(W1p + ((size_t)((kb*4 + kblk)*4 + quad)*NH + g16)*8);
        acc0 = __builtin_amdgcn_mfma_f32_16x16x32_bf16(a0, bb, acc0, 0, 0, 0);
        acc1 = __builtin_amdgcn_mfma_f32_16x16x32_bf16(a1, bb, acc1, 0, 0, 0);
      }
      __syncthreads();
    }
  }
  {
    float b1v = par[P_B1 + g16];
#pragma unroll
    for (int mt = 0; mt < 2; mt++) {
      f32x4 a = mt ? acc1 : acc0;
#pragma unroll
      for (int r = 0; r < 4; r++) {
        int row = mt*16 + quad*4 + r;
        if (row < NT) hbuf[row*128 + g16] = a[r] + b1v;
      }
    }
  }
  __syncthreads();

  // ---- phase 2: h = LN1(C) in place; row means -> g0s ----
  for (int r = w; r < NT; r += 8) {
    float v0 = hbuf[r*128 + lane], v1 = hbuf[r*128 + lane + 64];
    float s = v0 + v1, ss = v0*v0 + v1*v1;
#pragma unroll
    for (int off = 1; off <= 32; off <<= 1) {
      s += __shfl_xor(s, off, 64); ss += __shfl_xor(ss, off, 64);
    }
    float mean = s * (1.f/NH);
    float var = ss * (1.f/NH) - mean*mean;
    float rs = rsqrtf(var + LNEPS);
    float o0 = (v0 - mean) * rs * par[P_LNG + lane]      + par[P_LNB + lane];
    float o1 = (v1 - mean) * rs * par[P_LNG + lane + 64] + par[P_LNB + lane + 64];
    hbuf[r*128 + lane] = o0;
    hbuf[r*128 + lane + 64] = o1;
    float rm = o0 + o1;
#pragma unroll
    for (int off = 1; off <= 32; off <<= 1) rm += __shfl_xor(rm, off, 64);
    if (lane == 0) g0s[r] = rm * (1.f/NH);
  }
  __syncthreads();

  // ---- phase 3: gate = softmax(g0 @ T_W + T_b) ----
  if (tid < 32) {
    float y = -1e30f;
    if (tid < NT) {
      y = par[P_TB + tid];
      for (int t = 0; t < NT; t++) y += g0s[t] * par[P_TW + t*NT + tid];
    }
    float mx = y;
#pragma unroll
    for (int off = 16; off >= 1; off >>= 1) mx = fmaxf(mx, __shfl_xor(mx, off, 64));
    float e = (tid < NT) ? expf(y - mx) : 0.f;
    float s = e;
#pragma unroll
    for (int off = 16; off >= 1; off >>= 1) s += __shfl_xor(s, off, 64);
    if (tid < NT) sgate[tid] = e / s;
  }
  __syncthreads();

  // ---- phase 4: h2 = h * gate ----
#pragma unroll
  for (int it = 0; it < 2; it++) {
    int c = it*512 + tid;
    if (c < 960) {
      int row = c >> 5, i = c & 31;
      float gt = sgate[row];
      float4* p = (float4*)(hbuf + row*128 + i*4);
      float4 v = *p;
      v.x *= gt; v.y *= gt; v.z *= gt; v.w *= gt;
      *p = v;
    }
  }
  __syncthreads();

  // ---- phase 5: hn = LN2(h2) -> bf16; rows 30,31 zero ----
  for (int r = w; r < NT; r += 8) {
    float v0 = hbuf[r*128 + lane], v1 = hbuf[r*128 + lane + 64];
    float s = v0 + v1, ss = v0*v0 + v1*v1;
#pragma unroll
    for (int off = 1; off <= 32; off <<= 1) {
      s += __shfl_xor(s, off, 64); ss += __shfl_xor(ss, off, 64);
    }
    float mean = s * (1.f/NH);
    float var = ss * (1.f/NH) - mean*mean;
    float rs = rsqrtf(var + LNEPS);
    hn[r*136 + lane]      = f2bf((v0 - mean) * rs * par[P_NG + lane]      + par[P_NB_ + lane]);
    hn[r*136 + lane + 64] = f2bf((v1 - mean) * rs * par[P_NG + lane + 64] + par[P_NB_ + lane + 64]);
  }
  if (tid < 256) hn[(NT + (tid >> 7))*136 + (tid & 127)] = 0;
  __syncthreads();

  // ---- phase 6: q, k, v — shared A-fragments, one col-group per wave ----
  {
    f32x4 q0 = {0.f,0.f,0.f,0.f}, q1 = q0, k0 = q0, k1 = q0, v0a = q0, v1a = q0;
#pragma unroll
    for (int ks = 0; ks < 4; ks++) {
      s16x8 a0 = *(const s16x8*)(hn + m_*136 + (ks*4 + quad)*8);
      s16x8 a1 = *(const s16x8*)(hn + (16 + m_)*136 + (ks*4 + quad)*8);
      size_t fo = ((size_t)(ks*4 + quad)*NH + g16)*8;
      s16x8 bq8 = *(const s16x8*)(Wqp + fo);
      q0 = __builtin_amdgcn_mfma_f32_16x16x32_bf16(a0, bq8, q0, 0, 0, 0);
      q1 = __builtin_amdgcn_mfma_f32_16x16x32_bf16(a1, bq8, q1, 0, 0, 0);
      s16x8 bk8 = *(const s16x8*)(Wkp + fo);
      k0 = __builtin_amdgcn_mfma_f32_16x16x32_bf16(a0, bk8, k0, 0, 0, 0);
      k1 = __builtin_amdgcn_mfma_f32_16x16x32_bf16(a1, bk8, k1, 0, 0, 0);
      s16x8 bv8 = *(const s16x8*)(Wvp + fo);
      v0a = __builtin_amdgcn_mfma_f32_16x16x32_bf16(a0, bv8, v0a, 0, 0, 0);
      v1a = __builtin_amdgcn_mfma_f32_16x16x32_bf16(a1, bv8, v1a, 0, 0, 0);
    }
    float bqv = par[P_BQ + g16], bkv = par[P_BK + g16], bvv = par[P_BV + g16];
#pragma unroll
    for (int mt = 0; mt < 2; mt++) {
      f32x4 qq = mt ? q1 : q0, kk = mt ? k1 : k0, vv = mt ? v1a : v0a;
      s16x4 vtp;
#pragma unroll
      for (int r = 0; r < 4; r++) {
        int row = mt*16 + quad*4 + r;
        qb[row*136 + g16]  = f2bf(qq[r] + bqv);
        kbf[row*136 + g16] = f2bf(kk[r] + bkv);
        vtp[r] = f2bf(vv[r] + bvv);
      }
      *(s16x4*)(vt + g16*32 + mt*16 + quad*4) = vtp;   // v^T, packed 8B write
    }
  }
  __syncthreads();

  // ---- phase 7: S = q @ k^T (waves 0-3, one 16x16 tile each) ----
  if (w < 4) {
    int mt = w >> 1, nt = w & 1;
    f32x4 sa = {0.f,0.f,0.f,0.f};
#pragma unroll
    for (int ks = 0; ks < 4; ks++) {
      s16x8 a   = *(const s16x8*)(qb  + (mt*16 + m_)*136 + (ks*4 + quad)*8);
      s16x8 bbv = *(const s16x8*)(kbf + (nt*16 + m_)*136 + (ks*4 + quad)*8);
      sa = __builtin_amdgcn_mfma_f32_16x16x32_bf16(a, bbv, sa, 0, 0, 0);
    }
#pragma unroll
    for (int r = 0; r < 4; r++)
      Sb[(mt*16 + quad*4 + r)*33 + nt*16 + m_] = sa[r];
  }
  __syncthreads();

  // ---- phase 8: parallel softmax (32 lanes per row, 2 passes) -> P bf16, pads zero ----
#pragma unroll
  for (int ps = 0; ps < 2; ps++) {
    int row = ps*16 + (tid >> 5);
    int col = tid & 31;
    if (row < NT) {
      float sv = (col < NT) ? Sb[row*33 + col] : -1e30f;
      float mx = sv;
#pragma unroll
      for (int off = 16; off >= 1; off >>= 1) mx = fmaxf(mx, __shfl_xor(mx, off, 32));
      float e = (col < NT) ? expf((sv - mx) * ATT_SCALE) : 0.f;
      float s = e;
#pragma unroll
      for (int off = 16; off >= 1; off >>= 1) s += __shfl_xor(s, off, 32);
      Pb[row*32 + col] = f2bf(e / s);
    } else {
      Pb[row*32 + col] = 0;                     // rows 30,31
    }
  }
  __syncthreads();

  // ---- phase 9: av = P @ v -> As (reused) ----
  {
    f32x4 a40 = {0.f,0.f,0.f,0.f}, a41 = a40;
    s16x8 pa0 = *(const s16x8*)(Pb + m_*32 + quad*8);
    s16x8 pa1 = *(const s16x8*)(Pb + (16 + m_)*32 + quad*8);
    s16x8 vb8 = *(const s16x8*)(vt + g16*32 + quad*8);
    a40 = __builtin_amdgcn_mfma_f32_16x16x32_bf16(pa0, vb8, a40, 0, 0, 0);
    a41 = __builtin_amdgcn_mfma_f32_16x16x32_bf16(pa1, vb8, a41, 0, 0, 0);
#pragma unroll
    for (int mt = 0; mt < 2; mt++) {
      f32x4 a = mt ? a41 : a40;
#pragma unroll
      for (int r = 0; r < 4; r++)
        As[(mt*16 + quad*4 + r)*136 + g16] = f2bf(a[r]);
    }
  }
  __syncthreads();

  // ---- phase 10: h3 = av @ Wo + bo + h2 -> hn; rows 30,31 zero ----
  {
    f32x4 o0 = {0.f,0.f,0.f,0.f}, o1 = o0;
#pragma unroll
    for (int ks = 0; ks < 4; ks++) {
      s16x8 a0 = *(const s16x8*)(As + m_*136 + (ks*4 + quad)*8);
      s16x8 a1 = *(const s16x8*)(As + (16 + m_)*136 + (ks*4 + quad)*8);
      s16x8 bb = *(const s16x8*)(Wop + ((size_t)(ks*4 + quad)*NH + g16)*8);
      o0 = __builtin_amdgcn_mfma_f32_16x16x32_bf16(a0, bb, o0, 0, 0, 0);
      o1 = __builtin_amdgcn_mfma_f32_16x16x32_bf16(a1, bb, o1, 0, 0, 0);
    }
    float bov = par[P_BO + g16];
#pragma unroll
    for (int mt = 0; mt < 2; mt++) {
      f32x4 a = mt ? o1 : o0;
#pragma unroll
      for (int r = 0; r < 4; r++) {
        int row = mt*16 + quad*4 + r;
        if (row < NT)
          hn[row*136 + g16] = f2bf(a[r] + bov + hbuf[row*128 + g16]);
      }
    }
    if (tid < 256) hn[(NT + (tid >> 7))*136 + (tid & 127)] = 0;
  }
  __syncthreads();

  // ---- phase 11: out = h3 @ W2 + b2; fp32 path = direct stores, NO barriers ----
  for (int cg = 0; cg < 8; cg++) {
    f32x4 c0 = {0.f,0.f,0.f,0.f}, c1 = c0;
#pragma unroll
    for (int kblk = 0; kblk < 4; kblk++) {
      s16x8 a0 = *(const s16x8*)(hn + m_*136 + (kblk*4 + quad)*8);
      s16x8 a1 = *(const s16x8*)(hn + (16 + m_)*136 + (kblk*4 + quad)*8);
      s16x8 bb = *(const s16x8*)(W2p + ((size_t)(kblk*4 + quad)*ND + cg*128 + g16)*8);
      c0 = __builtin_amdgcn_mfma_f32_16x16x32_bf16(a0, bb, c0, 0, 0, 0);
      c1 = __builtin_amdgcn_mfma_f32_16x16x32_bf16(a1, bb, c1, 0, 0, 0);
    }
    float b2v = par[P_B2 + cg*128 + g16];
    if (isf32) {
      float* po = (float*)out + (size_t)b*NT*ND + cg*128 + g16;
#pragma unroll
      for (int mt = 0; mt < 2; mt++) {
        f32x4 a = mt ? c1 : c0;
#pragma unroll
        for (int r = 0; r < 4; r++) {
          int row = mt*16 + quad*4 + r;
          if (row < NT) po[(size_t)row*ND] = a[r] + b2v;
        }
      }
    } else {
#pragma unroll
      for (int mt = 0; mt < 2; mt++) {
        f32x4 a = mt ? c1 : c0;
#pragma unroll
        for (int r = 0; r < 4; r++)
          qb[(mt*16 + quad*4 + r)*136 + g16] = f2bf(a[r] + b2v);
      }
      __syncthreads();
      if (tid < 480) {
        int r = tid >> 4, cc = tid & 15;
        *(uint4*)((short*)out + ((size_t)b*NT + r)*ND + cg*128 + cc*8) =
            *(const uint4*)(qb + r*136 + cc*8);
      }
      __syncthreads();
    }
  }
}

// ================= fallback (verified previous kernel, used when ws too small) =================
__global__ __launch_bounds__(256) void fused_all(
    const void* __restrict__ x, const void* __restrict__ W1,
    const void* __restrict__ b1, const void* __restrict__ ln_g, const void* __restrict__ ln_b,
    const void* __restrict__ T_W, const void* __restrict__ T_b,
    const void* __restrict__ Wq, const void* __restrict__ bq,
    const void* __restrict__ Wk, const void* __restrict__ bk,
    const void* __restrict__ Wv, const void* __restrict__ bv,
    const void* __restrict__ Wo, const void* __restrict__ bo,
    const void* __restrict__ n_g, const void* __restrict__ n_b,
    const void* __restrict__ W2, const void* __restrict__ b2,
    void* __restrict__ out) {
  __shared__ __align__(16) short As[32*136];
  __shared__ __align__(16) float hbuf[NT*128];
  __shared__ float g0s[32];
  __shared__ float sgate[32];
  __shared__ __align__(16) short hn[32*136];
  __shared__ __align__(16) short qb[32*136];
  __shared__ __align__(16) short kbf[32*136];
  __shared__ __align__(16) short vt[NH*32];
  __shared__ float Sb[32*33];
  __shared__ __align__(16) short Pb[32*32];

  int tid = threadIdx.x, lane = tid & 63, w = tid >> 6;
  int m_ = lane & 15, quad = lane >> 4;
  int b = blockIdx.x;

  int isf32;
  {
    const unsigned short* u = (const unsigned short*)x;
    int pl = 0;
#pragma unroll
    for (int i = 0; i < 64; i++) {
      int e = (u[i] >> 7) & 0xFF;
      pl += (e >= 0x3A && e <= 0x43) ? 1 : 0;
    }
    isf32 = (pl < 48) ? 1 : 0;
  }
  const size_t xbase = (size_t)b * NT * ND;

  f32x4 acc[2][2];
#pragma unroll
  for (int mt = 0; mt < 2; mt++)
#pragma unroll
    for (int j = 0; j < 2; j++) acc[mt][j] = {0.f, 0.f, 0.f, 0.f};

  for (int kb = 0; kb < 8; kb++) {
    __syncthreads();
#pragma unroll
    for (int it = 0; it < 2; it++) {
      int c = it*256 + tid;
      int r = c >> 4, cc = c & 15;
      int rr = r > NT-1 ? NT-1 : r;
      size_t off = xbase + (size_t)rr*ND + kb*128 + cc*8;
      if (!isf32) {
        *(uint4*)(As + r*136 + cc*8) = *(const uint4*)((const short*)x + off);
      } else {
        const float* src = (const float*)x + off;
        float4 f0 = *(const float4*)src, f1 = *(const float4*)(src + 4);
        s16x8 t;
        t[0]=f2bf(f0.x); t[1]=f2bf(f0.y); t[2]=f2bf(f0.z); t[3]=f2bf(f0.w);
        t[4]=f2bf(f1.x); t[5]=f2bf(f1.y); t[6]=f2bf(f1.z); t[7]=f2bf(f1.w);
        *(s16x8*)(As + r*136 + cc*8) = t;
      }
    }
    __syncthreads();
#pragma unroll
    for (int kblk = 0; kblk < 4; kblk++) {
      s16x8 a0 = *(const s16x8*)(As + (m_)*136      + (kblk*4 + quad)*8);
      s16x8 a1 = *(const s16x8*)(As + (16 + m_)*136 + (kblk*4 + quad)*8);
#pragma unroll
      for (int j = 0; j < 2; j++) {
        s16x8 bb = ldfragB(W1, NH, (kb*4 + kblk)*32, (2*w + j)*16, m_, quad, isf32);
        acc[0][j] = __builtin_amdgcn_mfma_f32_16x16x32_bf16(a0, bb, acc[0][j], 0, 0, 0);
        acc[1][j] = __builtin_amdgcn_mfma_f32_16x16x32_bf16(a1, bb, acc[1][j], 0, 0, 0);
      }
    }
  }
  __syncthreads();
  {
    float b1v[2] = {ldp(b1, (2*w)*16 + m_, isf32), ldp(b1, (2*w+1)*16 + m_, isf32)};
#pragma unroll
    for (int mt = 0; mt < 2; mt++)
#pragma unroll
      for (int j = 0; j < 2; j++)
#pragma unroll
        for (int r = 0; r < 4; r++) {
          int row = mt*16 + quad*4 + r;
          if (row < NT)
            hbuf[row*128 + (2*w + j)*16 + m_] = acc[mt][j][r] + b1v[j];
        }
  }
  __syncthreads();

  for (int r = w; r < NT; r += 4) {
    float v0 = hbuf[r*128 + lane], v1 = hbuf[r*128 + lane + 64];
    float s = v0 + v1, ss = v0*v0 + v1*v1;
#pragma unroll
    for (int off = 1; off <= 32; off <<= 1) {
      s += __shfl_xor(s, off, 64); ss += __shfl_xor(ss, off, 64);
    }
    float mean = s * (1.f/NH);
    float var = ss * (1.f/NH) - mean*mean;
    float rs = rsqrtf(var + LNEPS);
    float o0 = (v0 - mean) * rs * ldp(ln_g, lane, isf32)      + ldp(ln_b, lane, isf32);
    float o1 = (v1 - mean) * rs * ldp(ln_g, lane + 64, isf32) + ldp(ln_b, lane + 64, isf32);
    hbuf[r*128 + lane] = o0;
    hbuf[r*128 + lane + 64] = o1;
    float rm = o0 + o1;
#pragma unroll
    for (int off = 1; off <= 32; off <<= 1) rm += __shfl_xor(rm, off, 64);
    if (lane == 0) g0s[r] = rm * (1.f/NH);
  }
  __syncthreads();

  if (tid < 32) {
    float y = -1e30f;
    if (tid < NT) {
      y = ldp(T_b, tid, isf32);
      for (int t = 0; t < NT; t++) y += g0s[t] * ldp(T_W, t*NT + tid, isf32);
    }
    float mx = y;
#pragma unroll
    for (int off = 16; off >= 1; off >>= 1) mx = fmaxf(mx, __shfl_xor(mx, off, 64));
    float e = (tid < NT) ? expf(y - mx) : 0.f;
    float s = e;
#pragma unroll
    for (int off = 16; off >= 1; off >>= 1) s += __shfl_xor(s, off, 64);
    if (tid < NT) sgate[tid] = e / s;
  }
  __syncthreads();

#pragma unroll
  for (int it = 0; it < 4; it++) {
    int c = it*256 + tid;
    if (c < 960) {
      int row = c >> 5, i = c & 31;
      float gt = sgate[row];
      float4* p = (float4*)(hbuf + row*128 + i*4);
      float4 v = *p;
      v.x *= gt; v.y *= gt; v.z *= gt; v.w *= gt;
      *p = v;
    }
  }
  __syncthreads();

  for (int r = w; r < NT; r += 4) {
    float v0 = hbuf[r*128 + lane], v1 = hbuf[r*128 + lane + 64];
    float s = v0 + v1, ss = v0*v0 + v1*v1;
#pragma unroll
    for (int off = 1; off <= 32; off <<= 1) {
      s += __shfl_xor(s, off, 64); ss += __shfl_xor(ss, off, 64);
    }
    float mean = s * (1.f/NH);
    float var = ss * (1.f/NH) - mean*mean;
    float rs = rsqrtf(var + LNEPS);
    hn[r*136 + lane]      = f2bf((v0 - mean) * rs * ldp(n_g, lane, isf32)      + ldp(n_b, lane, isf32));
    hn[r*136 + lane + 64] = f2bf((v1 - mean) * rs * ldp(n_g, lane + 64, isf32) + ldp(n_b, lane + 64, isf32));
  }
  hn[(30 + (tid >> 7))*136 + (tid & 127)] = 0;
  __syncthreads();

  {
    f32x4 a4[2][2];
    float bias2[2];
    mm32d(hn, Wq, bq, w, lane, isf32, a4, bias2);
#pragma unroll
    for (int mt = 0; mt < 2; mt++)
#pragma unroll
      for (int j = 0; j < 2; j++)
#pragma unroll
        for (int r = 0; r < 4; r++)
          qb[(mt*16 + quad*4 + r)*136 + (2*w + j)*16 + m_] = f2bf(a4[mt][j][r] + bias2[j]);
    mm32d(hn, Wk, bk, w, lane, isf32, a4, bias2);
#pragma unroll
    for (int mt = 0; mt < 2; mt++)
#pragma unroll
      for (int j = 0; j < 2; j++)
#pragma unroll
        for (int r = 0; r < 4; r++)
          kbf[(mt*16 + quad*4 + r)*136 + (2*w + j)*16 + m_] = f2bf(a4[mt][j][r] + bias2[j]);
    mm32d(hn, Wv, bv, w, lane, isf32, a4, bias2);
#pragma unroll
    for (int mt = 0; mt < 2; mt++)
#pragma unroll
      for (int j = 0; j < 2; j++)
#pragma unroll
        for (int r = 0; r < 4; r++)
          vt[((2*w + j)*16 + m_)*32 + mt*16 + quad*4 + r] = f2bf(a4[mt][j][r] + bias2[j]);
  }
  __syncthreads();

  {
    int mt = w >> 1, nt = w & 1;
    f32x4 sa = {0.f, 0.f, 0.f, 0.f};
#pragma unroll
    for (int ks = 0; ks < 4; ks++) {
      s16x8 a   = *(const s16x8*)(qb  + (mt*16 + m_)*136 + (ks*4 + quad)*8);
      s16x8 bbv = *(const s16x8*)(kbf + (nt*16 + m_)*136 + (ks*4 + quad)*8);
      sa = __builtin_amdgcn_mfma_f32_16x16x32_bf16(a, bbv, sa, 0, 0, 0);
    }
#pragma unroll
    for (int r = 0; r < 4; r++)
      Sb[(mt*16 + quad*4 + r)*33 + nt*16 + m_] = sa[r];
  }
  __syncthreads();

  if (tid < NT) {
    float mx = -1e30f;
    for (int jj = 0; jj < NT; jj++) {
      int j = tid + jj; if (j >= NT) j -= NT;
      mx = fmaxf(mx, Sb[tid*33 + j]);
    }
    float sum = 0.f;
    for (int jj = 0; jj < NT; jj++) {
      int j = tid + jj; if (j >= NT) j -= NT;
      float e = expf((Sb[tid*33 + j] - mx) * ATT_SCALE);
      Sb[tid*33 + j] = e; sum += e;
    }
    float rinv = 1.f / sum;
    for (int jj = 0; jj < NT; jj++) {
      int j = tid + jj; if (j >= NT) j -= NT;
      Pb[tid*32 + j] = f2bf(Sb[tid*33 + j] * rinv);
    }
    Pb[tid*32 + 30] = 0;
    Pb[tid*32 + 31] = 0;
  } else if (tid >= 64 && tid < 128) {
    int c = tid - 64;
    Pb[(30 + (c >> 5))*32 + (c & 31)] = 0;
  }
  __syncthreads();

  {
    f32x4 a4[2][2];
#pragma unroll
    for (int mt = 0; mt < 2; mt++)
#pragma unroll
      for (int j = 0; j < 2; j++) a4[mt][j] = {0.f, 0.f, 0.f, 0.f};
    s16x8 pa[2];
#pragma unroll
    for (int mt = 0; mt < 2; mt++)
      pa[mt] = *(const s16x8*)(Pb + (mt*16 + m_)*32 + quad*8);
#pragma unroll
    for (int j = 0; j < 2; j++) {
      int nh = (2*w + j)*16 + m_;
      s16x8 vb8 = *(const s16x8*)(vt + nh*32 + quad*8);
#pragma unroll
      for (int mt = 0; mt < 2; mt++)
        a4[mt][j] = __builtin_amdgcn_mfma_f32_16x16x32_bf16(pa[mt], vb8, a4[mt][j], 0, 0, 0);
    }
#pragma unroll
    for (int mt = 0; mt < 2; mt++)
#pragma unroll
      for (int j = 0; j < 2; j++)
#pragma unroll
        for (int r = 0; r < 4; r++)
          As[(mt*16 + quad*4 + r)*136 + (2*w + j)*16 + m_] = f2bf(a4[mt][j][r]);
  }
  __syncthreads();

  {
    f32x4 a4[2][2];
    float bias2[2];
    mm32d(As, Wo, bo, w, lane, isf32, a4, bias2);
#pragma unroll
    for (int mt = 0; mt < 2; mt++)
#pragma unroll
      for (int j = 0; j < 2; j++)
#pragma unroll
        for (int r = 0; r < 4; r++) {
          int row = mt*16 + quad*4 + r;
          if (row < NT) {
            int col = (2*w + j)*16 + m_;
            hn[row*136 + col] = f2bf(a4[mt][j][r] + bias2[j] + hbuf[row*128 + col]);
          }
        }
    hn[(30 + (tid >> 7))*136 + (tid & 127)] = 0;
  }
  __syncthreads();

  for (int cg = 0; cg < 8; cg++) {
    f32x4 a2[2][2];
#pragma unroll
    for (int mt = 0; mt < 2; mt++)
#pragma unroll
      for (int j = 0; j < 2; j++) a2[mt][j] = {0.f, 0.f, 0.f, 0.f};
#pragma unroll
    for (int kblk = 0; kblk < 4; kblk++) {
      s16x8 a0 = *(const s16x8*)(hn + (m_)*136      + (kblk*4 + quad)*8);
      s16x8 a1 = *(const s16x8*)(hn + (16 + m_)*136 + (kblk*4 + quad)*8);
#pragma unroll
      for (int j = 0; j < 2; j++) {
        s16x8 bb = ldfragB(W2, ND, kblk*32, cg*128 + (2*w + j)*16, m_, quad, isf32);
        a2[0][j] = __builtin_amdgcn_mfma_f32_16x16x32_bf16(a0, bb, a2[0][j], 0, 0, 0);
        a2[1][j] = __builtin_amdgcn_mfma_f32_16x16x32_bf16(a1, bb, a2[1][j], 0, 0, 0);
      }
    }
    float b2v[2] = {ldp(b2, cg*128 + (2*w)*16 + m_, isf32),
                    ldp(b2, cg*128 + (2*w+1)*16 + m_, isf32)};
    if (!isf32) {
#pragma unroll
      for (int mt = 0; mt < 2; mt++)
#pragma unroll
        for (int j = 0; j < 2; j++)
#pragma unroll
          for (int r = 0; r < 4; r++)
            qb[(mt*16 + quad*4 + r)*136 + (2*w + j)*16 + m_] = f2bf(a2[mt][j][r] + b2v[j]);
    }
    __syncthreads();
    if (!isf32) {
#pragma unroll
      for (int it = 0; it < 2; it++) {
        int c = it*256 + tid;
        if (c < 480) {
          int r = c >> 4, cc = c & 15;
          *(uint4*)((short*)out + ((size_t)b*NT + r)*ND + cg*128 + cc*8) =
              *(const uint4*)(qb + r*136 + cc*8);
        }
      }
    } else {
#pragma unroll
      for (int mt = 0; mt < 2; mt++)
#pragma unroll
        for (int j = 0; j < 2; j++)
#pragma unroll
          for (int r = 0; r < 4; r++) {
            int row = mt*16 + quad*4 + r;
            if (row < NT)
              ((float*)out)[((size_t)b*NT + row)*ND + cg*128 + (2*w + j)*16 + m_] =
                  a2[mt][j][r] + b2v[j];
          }
    }
    __syncthreads();
  }
}

extern "C" void kernel_launch(void* const* d_in, const int* in_sizes, int n_in,
                              void* d_out, int out_size, void* d_ws, size_t ws_size,
                              hipStream_t stream) {
  if (d_ws && ws_size >= (size_t)WS_NEED) {
    short* W1p = (short*)((char*)d_ws + WS_W1P);
    short* W2p = (short*)((char*)d_ws + WS_W2P);
    short* Wqp = (short*)((char*)d_ws + WS_WQP);
    short* Wkp = (short*)((char*)d_ws + WS_WKP);
    short* Wvp = (short*)((char*)d_ws + WS_WVP);
    short* Wop = (short*)((char*)d_ws + WS_WOP);
    float* par = (float*)((char*)d_ws + WS_PAR);
    // 40960 weight frags + 3108 params = 44068 work items
    repack<<<173, 256, 0, stream>>>(
        d_in[0],
        d_in[1], d_in[7], d_in[9], d_in[11], d_in[13], d_in[17],
        d_in[2], d_in[3], d_in[4], d_in[5], d_in[6],
        d_in[8], d_in[10], d_in[12], d_in[14], d_in[15], d_in[16], d_in[18],
        W1p, W2p, Wqp, Wkp, Wvp, Wop, par);
    fused_pk<<<NB, 512, 0, stream>>>(d_in[0], W1p, W2p, Wqp, Wkp, Wvp, Wop, par, d_out);
  } else {
    fused_all<<<NB, 256, 0, stream>>>(
        d_in[0], d_in[1], d_in[2], d_in[3], d_in[4], d_in[5], d_in[6],
        d_in[7], d_in[8], d_in[9], d_in[10], d_in[11], d_in[12], d_in[13],
        d_in[14], d_in[15], d_in[16], d_in[17], d_in[18], d_out);
  }
}